// Round 1
// baseline (1161.805 us; speedup 1.0000x reference)
//
#include <hip/hip_runtime.h>

#define XS 68            // padded LDS row stride (words), 4-aligned for b128
#define EPSV 1e-5f
#define CLS_SZ (32768*6)

__device__ __forceinline__ float4 ld4s(const float* p) {
  return *reinterpret_cast<const float4*>(p);
}

// acc[4][8] += X[k][4ag..4ag+3] (x) W[k][{4jg..4jg+3, 64+4jg..64+4jg+3}], k=0..127
__device__ __forceinline__ void gemm_k128(const float* __restrict__ X,
                                          const float* __restrict__ W,
                                          float acc[4][8], int ag, int jg)
{
  const float* xp = X + 4*ag;
  const float* wp = W + 4*jg;
  #pragma unroll 4
  for (int k = 0; k < 128; ++k) {
    float4 a  = ld4s(xp + k*XS);
    float4 wl = ld4s(wp + k*128);
    float4 wh = ld4s(wp + k*128 + 64);
    float av[4] = {a.x, a.y, a.z, a.w};
    float wv[8] = {wl.x, wl.y, wl.z, wl.w, wh.x, wh.y, wh.z, wh.w};
    #pragma unroll
    for (int r = 0; r < 4; ++r)
      #pragma unroll
      for (int c = 0; c < 8; ++c)
        acc[r][c] = fmaf(av[r], wv[c], acc[r][c]);
  }
}

__device__ __forceinline__ void zero_acc(float acc[4][8]) {
  #pragma unroll
  for (int r = 0; r < 4; ++r)
    #pragma unroll
    for (int c = 0; c < 8; ++c) acc[r][c] = 0.f;
}

// GroupNorm(1,128) stats over channel axis; rows = 4*ag+r, channels split per jg
__device__ __forceinline__ void gn_stats(const float acc[4][8], float* PS1, float* PS2,
                                         float* MEANs, float* RSTDs, int ag, int jg, int tid)
{
  #pragma unroll
  for (int r = 0; r < 4; ++r) {
    float s = 0.f, q = 0.f;
    #pragma unroll
    for (int c = 0; c < 8; ++c) { float v = acc[r][c]; s += v; q += v*v; }
    int row = 4*ag + r;
    PS1[row*17 + jg] = s;
    PS2[row*17 + jg] = q;
  }
  __syncthreads();
  if (tid < 64) {
    float s = 0.f, q = 0.f;
    #pragma unroll
    for (int j = 0; j < 16; ++j) { s += PS1[tid*17 + j]; q += PS2[tid*17 + j]; }
    float mu  = s * 0.0078125f;
    float var = q * 0.0078125f - mu*mu;
    MEANs[tid] = mu;
    RSTDs[tid] = rsqrtf(var + EPSV);
  }
  __syncthreads();
}

// ---------------- Kernel A: per-mode pred heads -> unsorted reg ----------------
__global__ void __launch_bounds__(256) pred_kernel(
    const float* __restrict__ actors, const float* __restrict__ ctrs,
    const float* __restrict__ W1, const float* __restrict__ g1v, const float* __restrict__ b1v,
    const float* __restrict__ W2, const float* __restrict__ g2v, const float* __restrict__ b2v,
    const float* __restrict__ Wo, const float* __restrict__ bov,
    float* __restrict__ out_reg)
{
  __shared__ float XT[128*XS];   // actors tile, transposed [ch][row]
  __shared__ float YT[128*XS];   // activation ping buffer
  __shared__ float WL[128*128];  // current weight matrix
  __shared__ float PS1[64*17], PS2[64*17], MEANs[64], RSTDs[64];

  const int tid = threadIdx.x;
  const int jg = tid & 15, ag = tid >> 4;
  const int m  = blockIdx.y;
  const int n0 = blockIdx.x * 64;

  // stage actors tile (transposed) + W1
  for (int i = tid; i < 64*128; i += 256) {
    int a = i >> 7, ch = i & 127;
    XT[ch*XS + a] = actors[(size_t)(n0 + a)*128 + ch];
  }
  {
    const float4* src = reinterpret_cast<const float4*>(W1 + (size_t)m*16384);
    float4* dst = reinterpret_cast<float4*>(WL);
    for (int i = tid; i < 4096; i += 256) dst[i] = src[i];
  }
  __syncthreads();

  float acc[4][8];

  // ---- layer 1: relu(GN(actors @ W1)) -> YT ----
  zero_acc(acc);
  gemm_k128(XT, WL, acc, ag, jg);
  gn_stats(acc, PS1, PS2, MEANs, RSTDs, ag, jg, tid);
  {
    const float4* src = reinterpret_cast<const float4*>(W2 + (size_t)m*16384);
    float4* dst = reinterpret_cast<float4*>(WL);
    for (int i = tid; i < 4096; i += 256) dst[i] = src[i];
  }
  {
    const float* g = g1v + m*128; const float* b = b1v + m*128;
    #pragma unroll
    for (int r = 0; r < 4; ++r) {
      int row = 4*ag + r;
      float mu = MEANs[row], rs = RSTDs[row];
      #pragma unroll
      for (int c = 0; c < 8; ++c) {
        int ch = (c < 4) ? 4*jg + c : 64 + 4*jg + (c - 4);
        float v = (acc[r][c] - mu) * rs * g[ch] + b[ch];
        YT[ch*XS + row] = fmaxf(v, 0.f);
      }
    }
  }
  __syncthreads();

  // ---- layer 2: relu(GN(h1 @ W2) + actors) -> YT ----
  zero_acc(acc);
  gemm_k128(YT, WL, acc, ag, jg);
  gn_stats(acc, PS1, PS2, MEANs, RSTDs, ag, jg, tid);
  // load Wo padded to [128][64]
  for (int i = tid; i < 128*64; i += 256) {
    int k = i >> 6, j = i & 63;
    WL[k*64 + j] = (j < 60) ? Wo[(size_t)m*7680 + k*60 + j] : 0.f;
  }
  {
    const float* g = g2v + m*128; const float* b = b2v + m*128;
    #pragma unroll
    for (int r = 0; r < 4; ++r) {
      int row = 4*ag + r;
      float mu = MEANs[row], rs = RSTDs[row];
      #pragma unroll
      for (int c = 0; c < 8; ++c) {
        int ch = (c < 4) ? 4*jg + c : 64 + 4*jg + (c - 4);
        float v = (acc[r][c] - mu) * rs * g[ch] + b[ch];
        v += XT[ch*XS + row];                 // residual
        YT[ch*XS + row] = fmaxf(v, 0.f);
      }
    }
  }
  __syncthreads();

  // ---- output layer: h @ Wo + bo + ctr -> reg (unsorted) ----
  float acc3[4][4];
  #pragma unroll
  for (int r = 0; r < 4; ++r)
    #pragma unroll
    for (int c = 0; c < 4; ++c) acc3[r][c] = 0.f;
  {
    const float* xp = YT + 4*ag;
    const float* wp = WL + 4*jg;
    #pragma unroll 4
    for (int k = 0; k < 128; ++k) {
      float4 a = ld4s(xp + k*XS);
      float4 w = ld4s(wp + k*64);
      float av[4] = {a.x, a.y, a.z, a.w};
      float wv[4] = {w.x, w.y, w.z, w.w};
      #pragma unroll
      for (int r = 0; r < 4; ++r)
        #pragma unroll
        for (int c = 0; c < 4; ++c)
          acc3[r][c] = fmaf(av[r], wv[c], acc3[r][c]);
    }
  }
  int j0 = 4*jg;
  #pragma unroll
  for (int r = 0; r < 4; ++r) {
    int n = n0 + 4*ag + r;
    float cx = ctrs[2*n], cy = ctrs[2*n+1];
    #pragma unroll
    for (int c = 0; c < 4; ++c) {
      int j = j0 + c;
      if (j < 60) {
        float v = acc3[r][c] + bov[m*60 + j] + ((j & 1) ? cy : cx);
        out_reg[(size_t)n*360 + m*60 + j] = v;
      }
    }
  }
}

// ---------------- Kernel B: AttDest + cls head -> unsorted cls ----------------
__global__ void __launch_bounds__(256) att_cls_kernel(
    const float* __restrict__ actors, const float* __restrict__ ctrs,
    const float* __restrict__ dW1, const float* __restrict__ db1,
    const float* __restrict__ dW2, const float* __restrict__ dg2, const float* __restrict__ db2,
    const float* __restrict__ aW, const float* __restrict__ aG, const float* __restrict__ aB,
    const float* __restrict__ cW1, const float* __restrict__ cg1, const float* __restrict__ cb1,
    const float* __restrict__ cW2, const float* __restrict__ cg2, const float* __restrict__ cb2,
    const float* __restrict__ cWo, const float* __restrict__ cbo,
    const float* __restrict__ reg, float* __restrict__ cls_out)
{
  __shared__ float XT[128*XS];
  __shared__ float YT[128*XS];
  __shared__ float WL[128*128];
  __shared__ float PS1[64*17], PS2[64*17], MEANs[64], RSTDs[64];
  __shared__ float D0[128];

  const int tid = threadIdx.x;
  const int jg = tid & 15, ag = tid >> 4;
  const int r0 = blockIdx.x * 64;

  // phase 0: dist0 = ctr - reg_last
  if (tid < 64) {
    int rg = r0 + tid;
    int n = rg / 6, mm = rg - 6*n;
    size_t base = (size_t)n*360 + mm*60;
    D0[tid]      = ctrs[2*n]     - reg[base + 58];
    D0[64 + tid] = ctrs[2*n + 1] - reg[base + 59];
  }
  {
    const float4* src = reinterpret_cast<const float4*>(dW2);
    float4* dst = reinterpret_cast<float4*>(WL);
    for (int i = tid; i < 4096; i += 256) dst[i] = src[i];
  }
  __syncthreads();

  // dist1 = relu(dist0 @ dW1 + db1) -> XT
  #pragma unroll
  for (int r = 0; r < 4; ++r) {
    int row = 4*ag + r;
    float dx = D0[row], dy = D0[64 + row];
    #pragma unroll
    for (int c = 0; c < 8; ++c) {
      int ch = (c < 4) ? 4*jg + c : 64 + 4*jg + (c - 4);
      float v = fmaf(dx, dW1[ch], fmaf(dy, dW1[128 + ch], db1[ch]));
      XT[ch*XS + row] = fmaxf(v, 0.f);
    }
  }
  __syncthreads();

  float acc[4][8];

  // phase 1: dist2 = relu(GN(dist1 @ dW2)) -> YT ; then WL <- aW[0:128]
  zero_acc(acc);
  gemm_k128(XT, WL, acc, ag, jg);
  gn_stats(acc, PS1, PS2, MEANs, RSTDs, ag, jg, tid);
  {
    const float4* src = reinterpret_cast<const float4*>(aW);
    float4* dst = reinterpret_cast<float4*>(WL);
    for (int i = tid; i < 4096; i += 256) dst[i] = src[i];
  }
  #pragma unroll
  for (int r = 0; r < 4; ++r) {
    int row = 4*ag + r;
    float mu = MEANs[row], rs = RSTDs[row];
    #pragma unroll
    for (int c = 0; c < 8; ++c) {
      int ch = (c < 4) ? 4*jg + c : 64 + 4*jg + (c - 4);
      float v = (acc[r][c] - mu) * rs * dg2[ch] + db2[ch];
      YT[ch*XS + row] = fmaxf(v, 0.f);
    }
  }
  __syncthreads();

  // phase 2a: acc = dist2 @ aW_lo
  zero_acc(acc);
  gemm_k128(YT, WL, acc, ag, jg);
  __syncthreads();
  // stage agts into XT, aW_hi into WL
  for (int i = tid; i < 64*128; i += 256) {
    int rl = i >> 7, ch = i & 127;
    int n = (r0 + rl) / 6;
    XT[ch*XS + rl] = actors[(size_t)n*128 + ch];
  }
  {
    const float4* src = reinterpret_cast<const float4*>(aW + 128*128);
    float4* dst = reinterpret_cast<float4*>(WL);
    for (int i = tid; i < 4096; i += 256) dst[i] = src[i];
  }
  __syncthreads();
  // phase 2b: acc += agts @ aW_hi ; feats = relu(GN(acc)) -> YT ; WL <- cls_W1
  gemm_k128(XT, WL, acc, ag, jg);
  gn_stats(acc, PS1, PS2, MEANs, RSTDs, ag, jg, tid);
  {
    const float4* src = reinterpret_cast<const float4*>(cW1);
    float4* dst = reinterpret_cast<float4*>(WL);
    for (int i = tid; i < 4096; i += 256) dst[i] = src[i];
  }
  #pragma unroll
  for (int r = 0; r < 4; ++r) {
    int row = 4*ag + r;
    float mu = MEANs[row], rs = RSTDs[row];
    #pragma unroll
    for (int c = 0; c < 8; ++c) {
      int ch = (c < 4) ? 4*jg + c : 64 + 4*jg + (c - 4);
      float v = (acc[r][c] - mu) * rs * aG[ch] + aB[ch];
      YT[ch*XS + row] = fmaxf(v, 0.f);   // feats (kept for residual)
    }
  }
  __syncthreads();

  // phase 3: c1 = relu(GN(feats @ cls_W1)) -> XT ; WL <- cls_W2
  zero_acc(acc);
  gemm_k128(YT, WL, acc, ag, jg);
  gn_stats(acc, PS1, PS2, MEANs, RSTDs, ag, jg, tid);
  {
    const float4* src = reinterpret_cast<const float4*>(cW2);
    float4* dst = reinterpret_cast<float4*>(WL);
    for (int i = tid; i < 4096; i += 256) dst[i] = src[i];
  }
  #pragma unroll
  for (int r = 0; r < 4; ++r) {
    int row = 4*ag + r;
    float mu = MEANs[row], rs = RSTDs[row];
    #pragma unroll
    for (int c = 0; c < 8; ++c) {
      int ch = (c < 4) ? 4*jg + c : 64 + 4*jg + (c - 4);
      float v = (acc[r][c] - mu) * rs * cg1[ch] + cb1[ch];
      XT[ch*XS + row] = fmaxf(v, 0.f);
    }
  }
  __syncthreads();

  // phase 4: c2 = GN(c1 @ cls_W2); c = relu(c2 + feats); cls = c @ cls_Wo + bo
  zero_acc(acc);
  gemm_k128(XT, WL, acc, ag, jg);
  gn_stats(acc, PS1, PS2, MEANs, RSTDs, ag, jg, tid);
  #pragma unroll
  for (int r = 0; r < 4; ++r) {
    int row = 4*ag + r;
    float mu = MEANs[row], rs = RSTDs[row];
    float p = 0.f;
    #pragma unroll
    for (int c = 0; c < 8; ++c) {
      int ch = (c < 4) ? 4*jg + c : 64 + 4*jg + (c - 4);
      float v = (acc[r][c] - mu) * rs * cg2[ch] + cb2[ch];
      v = fmaxf(v + YT[ch*XS + row], 0.f);
      p = fmaf(v, cWo[ch], p);
    }
    PS1[row*17 + jg] = p;
  }
  __syncthreads();
  if (tid < 64) {
    float s = 0.f;
    #pragma unroll
    for (int j = 0; j < 16; ++j) s += PS1[tid*17 + j];
    cls_out[r0 + tid] = s + cbo[0];
  }
}

// ---------------- Kernel C: per-actor stable descending sort + permute ----------------
__global__ void __launch_bounds__(256) sort_kernel(float* __restrict__ out)
{
  __shared__ float RL[64*360];
  __shared__ float CL[64*6];
  __shared__ float CS[64*6];
  __shared__ int   ORD[64*6];

  const int tid = threadIdx.x;
  const int n0 = blockIdx.x * 64;
  float* regp = out + CLS_SZ;

  for (int i = tid; i < 64*360; i += 256) RL[i] = regp[(size_t)n0*360 + i];
  for (int i = tid; i < 384; i += 256)    CL[i] = out[n0*6 + i];
  __syncthreads();

  if (tid < 64) {
    float v[6];
    #pragma unroll
    for (int m2 = 0; m2 < 6; ++m2) v[m2] = CL[tid*6 + m2];
    int used = 0;
    for (int j = 0; j < 6; ++j) {
      int best = -1; float bv = 0.f;
      for (int m2 = 0; m2 < 6; ++m2) {
        if (used & (1 << m2)) continue;
        if (best < 0 || v[m2] > bv) { best = m2; bv = v[m2]; }  // stable: strict >
      }
      used |= (1 << best);
      ORD[tid*6 + j] = best;
      CS[tid*6 + j] = bv;
    }
  }
  __syncthreads();

  for (int i = tid; i < 384; i += 256) out[n0*6 + i] = CS[i];
  for (int i = tid; i < 64*360; i += 256) {
    int rl = i / 360, rem = i - rl*360;
    int slot = rem / 60, j = rem - slot*60;
    out[CLS_SZ + (size_t)n0*360 + i] = RL[rl*360 + ORD[rl*6 + slot]*60 + j];
  }
}

extern "C" void kernel_launch(void* const* d_in, const int* in_sizes, int n_in,
                              void* d_out, int out_size, void* d_ws, size_t ws_size,
                              hipStream_t stream)
{
  (void)in_sizes; (void)n_in; (void)out_size; (void)d_ws; (void)ws_size;
  const float* actors = (const float*)d_in[0];
  const float* ctrs   = (const float*)d_in[1];
  // d_in[2] = actor_idcs (identity partition; unused by the math)
  const float* pW1 = (const float*)d_in[3];
  const float* pg1 = (const float*)d_in[4];
  const float* pb1 = (const float*)d_in[5];
  const float* pW2 = (const float*)d_in[6];
  const float* pg2 = (const float*)d_in[7];
  const float* pb2 = (const float*)d_in[8];
  const float* pWo = (const float*)d_in[9];
  const float* pbo = (const float*)d_in[10];
  const float* cW1 = (const float*)d_in[11];
  const float* cg1 = (const float*)d_in[12];
  const float* cb1 = (const float*)d_in[13];
  const float* cW2 = (const float*)d_in[14];
  const float* cg2 = (const float*)d_in[15];
  const float* cb2 = (const float*)d_in[16];
  const float* cWo = (const float*)d_in[17];
  const float* cbo = (const float*)d_in[18];
  const float* dW1 = (const float*)d_in[19];
  const float* db1 = (const float*)d_in[20];
  const float* dW2 = (const float*)d_in[21];
  const float* dg2 = (const float*)d_in[22];
  const float* db2 = (const float*)d_in[23];
  const float* aW  = (const float*)d_in[24];
  const float* aG  = (const float*)d_in[25];
  const float* aB  = (const float*)d_in[26];

  float* out = (float*)d_out;
  float* out_reg = out + CLS_SZ;

  dim3 gA(512, 6);
  pred_kernel<<<gA, 256, 0, stream>>>(actors, ctrs, pW1, pg1, pb1, pW2, pg2, pb2,
                                      pWo, pbo, out_reg);
  att_cls_kernel<<<3072, 256, 0, stream>>>(actors, ctrs,
                                           dW1, db1, dW2, dg2, db2,
                                           aW, aG, aB,
                                           cW1, cg1, cb1, cW2, cg2, cb2, cWo, cbo,
                                           out_reg, out);
  sort_kernel<<<512, 256, 0, stream>>>(out);
}